// Round 22
// baseline (75.938 us; speedup 1.0000x reference)
//
#include <hip/hip_runtime.h>
#include <hip/hip_bf16.h>
#include <math.h>

typedef __attribute__((ext_vector_type(8))) short short8;
typedef __attribute__((ext_vector_type(4))) float f32x4;

#define T_TOK 2048
#define D_DIM 512
#define F_DIM 2048
#define E_NUM 8
#define MAXT1 40   // sum_e ceil(cnt_e/64) upper bound
#define MAXT32 80  // sum_e ceil(cnt_e/32) upper bound (64 + 8 rounding, padded)

__device__ __forceinline__ unsigned short f2bf(float f) {
  union { float f; unsigned u; } c; c.f = f;
  unsigned u = c.u;
  return (unsigned short)((u + 0x7fffu + ((u >> 16) & 1u)) >> 16);
}

__device__ __forceinline__ void gld16(const void* g, void* l) {
  __builtin_amdgcn_global_load_lds((const __attribute__((address_space(1))) int*)g,
                                   (__attribute__((address_space(3))) int*)l, 16, 0, 0);
}

// ---- prep: route (blocks 0..255) + wfrag1 W1/W3 dbuf 2-tiles (256..1279) ----
__global__ __launch_bounds__(256) void k_prep(const float* __restrict__ xin,
                                              const float* __restrict__ Wg,
                                              const float* __restrict__ W1,
                                              const float* __restrict__ W3,
                                              int* __restrict__ jbuf,
                                              float* __restrict__ wbuf,
                                              unsigned short* __restrict__ xb,
                                              unsigned short* __restrict__ w1f,
                                              unsigned short* __restrict__ w3f) {
  __shared__ float4 tile4[2][64 * 32];   // 64 KB (route blocks don't touch it)
  int bz = blockIdx.x, tid = threadIdx.x;

  if (bz < 256) {
    int gid = bz * 256 + tid;
    int t = gid >> 5, seg = gid & 31;
    const float* xp = xin + (size_t)t * D_DIM + seg * 16;
    unsigned short* xo = xb + (size_t)t * D_DIM + seg * 16;
    float acc[8];
#pragma unroll
    for (int e = 0; e < 8; ++e) acc[e] = 0.f;
#pragma unroll
    for (int i = 0; i < 4; ++i) {
      float4 v = *(const float4*)(xp + i * 4);
      ushort4 o;
      o.x = f2bf(v.x); o.y = f2bf(v.y); o.z = f2bf(v.z); o.w = f2bf(v.w);
      *(ushort4*)(xo + i * 4) = o;
      const float* xs = (const float*)&v;
#pragma unroll
      for (int q = 0; q < 4; ++q) {
        int d = seg * 16 + i * 4 + q;
        const float4* wr = (const float4*)(Wg + (size_t)d * 8);
        float4 w0 = wr[0], w1 = wr[1];
        acc[0] += xs[q] * w0.x; acc[1] += xs[q] * w0.y;
        acc[2] += xs[q] * w0.z; acc[3] += xs[q] * w0.w;
        acc[4] += xs[q] * w1.x; acc[5] += xs[q] * w1.y;
        acc[6] += xs[q] * w1.z; acc[7] += xs[q] * w1.w;
      }
    }
#pragma unroll
    for (int off = 1; off < 32; off <<= 1)
#pragma unroll
      for (int e = 0; e < 8; ++e) acc[e] += __shfl_xor(acc[e], off);
    if (seg == 0) {
      float l0 = -1e30f, l1 = -1e30f; int i0 = 0, i1 = 0;
#pragma unroll
      for (int e = 0; e < 8; ++e) {
        float l = acc[e];
        if (l > l0) { l1 = l0; i1 = i0; l0 = l; i0 = e; }
        else if (l > l1) { l1 = l; i1 = e; }
      }
      int j; float w;
      if (i0 > i1) { j = i0; w = 1.f / (1.f + expf(l1 - l0)); }
      else         { j = i1; w = 1.f / (1.f + expf(l0 - l1)); }
      jbuf[t] = j; wbuf[t] = w;
    }
    return;
  }

  // ---- wfrag1: W1/W3 [512][2048] -> frag bf16; 2 k-tiles per block, dbuf ----
  int idx = bz - 256;            // [0,1024)
  int z = idx >> 6, rem = idx & 63;
  const int K = 512, N = 2048;
  int n0 = (rem & 15) * 128, k0 = (rem >> 4) * 128;
  size_t zsz = (size_t)(K / 32) * (N / 16) * 512;
  const float* in; unsigned short* out;
  if (z < 8) { in = W1 + (size_t)z * K * N;       out = w1f + (size_t)z * zsz; }
  else       { in = W3 + (size_t)(z - 8) * K * N; out = w3f + (size_t)(z - 8) * zsz; }

  int lr = tid >> 5, lc = tid & 31;
  int wv = tid >> 6, l = tid & 63;
  int n4l = (l & 15) >> 2, nr = l & 3, kg = (l >> 4) * 8;

  auto loadT = [&](int buf, int kb0) {
#pragma unroll
    for (int it = 0; it < 8; ++it) {
      int row = it * 8 + lr;
      float4 v = *(const float4*)(in + (size_t)(kb0 + row) * N + n0 + lc * 4);
      tile4[buf][row * 32 + ((lc + (row >> 3) * 4) & 31)] = v;   // rotation swizzle
    }
  };
  auto storeT = [&](int buf, int kb0) {
    const float* tf = (const float*)&tile4[buf][0];
#pragma unroll
    for (int q = 0; q < 4; ++q) {
      int fid = wv * 4 + q;
      int nb = fid >> 1, kb = fid & 1;
      int n4 = nb * 4 + n4l;
      short8 o;
#pragma unroll
      for (int j = 0; j < 8; ++j) {
        int k = kb * 32 + kg + j;
        int slot = k * 32 + ((n4 + (k >> 3) * 4) & 31);
        o[j] = (short)f2bf(tf[slot * 4 + nr]);
      }
      unsigned short* op = out + (((size_t)(n0 / 16 + nb) * (K / 32)) + (kb0 / 32 + kb)) * 512 + l * 8;
      *(short8*)op = o;
    }
  };

  loadT(0, k0);
  __syncthreads();
  loadT(1, k0 + 64);
  storeT(0, k0);
  __syncthreads();
  storeT(1, k0 + 64);
}

// ---- bucket: counts, bases, token list, tile lists (BM=64 for ffn2, BM=32 for ffn1) ----
__global__ __launch_bounds__(256) void k_bucket(const int* __restrict__ jbuf,
                                                int* __restrict__ cntp,
                                                int* __restrict__ basep,
                                                int* __restrict__ list,
                                                int* __restrict__ tl1,
                                                int* __restrict__ tl32,
                                                int* __restrict__ ntl) {
  __shared__ int scnt[8], scur[8];
  int tid = threadIdx.x;
  if (tid < 8) scnt[tid] = 0;
  __syncthreads();
  for (int t = tid; t < T_TOK; t += 256) atomicAdd(&scnt[jbuf[t]], 1);
  __syncthreads();
  if (tid == 0) {
    int run = 0;
    for (int e = 0; e < 8; ++e) {
      cntp[e] = scnt[e]; basep[e] = run; scur[e] = run;
      run += scnt[e];
    }
    int n1 = 0, bb = 0;
    for (int e = 0; e < 8; ++e) {
      for (int m = 0; m < scnt[e]; m += 64) tl1[n1++] = (e << 16) | (bb + m);
      bb += scnt[e];
    }
    ntl[0] = n1;
    int n2 = 0; bb = 0;
    for (int e = 0; e < 8; ++e) {
      for (int m = 0; m < scnt[e]; m += 32) tl32[n2++] = (e << 16) | (bb + m);
      bb += scnt[e];
    }
    ntl[1] = n2;
  }
  __syncthreads();
  for (int t = tid; t < T_TOK; t += 256) {
    int j = jbuf[t];
    int p = atomicAdd(&scur[j], 1);
    list[p] = t;
  }
}

// ---- fused: ffn1 BM=32, 4 blocks/CU (0..2559) + wfrag2 single-buf (2560..3583) ----
__global__ __launch_bounds__(256, 4) void k_ffn1w2(const unsigned short* __restrict__ xb,
                                                   const unsigned short* __restrict__ w1f,
                                                   const unsigned short* __restrict__ w3f,
                                                   const float* __restrict__ W2,
                                                   unsigned short* __restrict__ w2f,
                                                   const int* __restrict__ cntp,
                                                   const int* __restrict__ basep,
                                                   const int* __restrict__ list,
                                                   const int* __restrict__ tl32,
                                                   const int* __restrict__ ntl,
                                                   unsigned short* __restrict__ hbuf) {
  __shared__ __align__(16) unsigned short sA[32 * 512];   // 32 KB (ffn1 A / wfrag2 tile)
  int tid = threadIdx.x, wv = tid >> 6, l = tid & 63;

  if (blockIdx.x >= 2560) {
    // ---- wfrag2: W2 [2048][512] -> frag bf16; one 64k x 128n tile, single-buf ----
    int idx = blockIdx.x - 2560;   // [0,1024)
    int z = idx >> 7, rem = idx & 127;
    const int K = 2048, N = 512;
    int n0 = (rem & 3) * 128, k0 = (rem >> 2) * 64;
    size_t zsz = (size_t)(K / 32) * (N / 16) * 512;
    const float* in = W2 + (size_t)z * K * N;
    unsigned short* out = w2f + (size_t)z * zsz;
    float4* tile4 = (float4*)sA;   // [64*32] = 32 KB

    int lr = tid >> 5, lc = tid & 31;
    int n4l = (l & 15) >> 2, nr = l & 3, kg = (l >> 4) * 8;
#pragma unroll
    for (int it = 0; it < 8; ++it) {
      int row = it * 8 + lr;
      float4 v = *(const float4*)(in + (size_t)(k0 + row) * N + n0 + lc * 4);
      tile4[row * 32 + ((lc + (row >> 3) * 4) & 31)] = v;
    }
    __syncthreads();
    const float* tf = (const float*)tile4;
#pragma unroll
    for (int q = 0; q < 4; ++q) {
      int fid = wv * 4 + q;
      int nb = fid >> 1, kb = fid & 1;
      int n4 = nb * 4 + n4l;
      short8 o;
#pragma unroll
      for (int j = 0; j < 8; ++j) {
        int k = kb * 32 + kg + j;
        int slot = k * 32 + ((n4 + (k >> 3) * 4) & 31);
        o[j] = (short)f2bf(tf[slot * 4 + nr]);
      }
      unsigned short* op = out + (((size_t)(n0 / 16 + nb) * (K / 32)) + (k0 / 32 + kb)) * 512 + l * 8;
      *(short8*)op = o;
    }
    return;
  }

  // ---- ffn1: BM=32; A staged once (32 KB); wave owns 32 rows x 16 cols; P/Q ping-pong ----
  int L = blockIdx.x;
  int b = (L & 7) * 320 + (L >> 3);    // XCD c owns y-groups [4c,4c+4) x all m-tiles
  int x = b % 80, y = b / 80;          // x: 32-row m-tile, y: 64-col group [0,32)
  if (x >= ntl[1]) return;
  int pk = tl32[x];
  int e = pk >> 16, g0 = pk & 0xffff;
  int lim = basep[e] + cntp[e];

  // one-time A stage: wave wv stages rows wv*8..+7 (swizzled source slots)
#pragma unroll
  for (int it = 0; it < 8; ++it) {
    int row = wv * 8 + it;
    int gr = g0 + row; if (gr >= lim) gr = lim - 1;
    int tok = list[gr];
    int slot = (l & 56) | ((l & 7) ^ (row & 7));
    gld16(xb + (size_t)tok * D_DIM + slot * 8, sA + row * 512);
  }

  // per-wave private B fragment column block: nb = y*4 + wv
  const unsigned short* w1b = w1f + ((size_t)(e * 128 + y * 4 + wv) * 16) * 512 + l * 8;
  const unsigned short* w3b = w3f + ((size_t)(e * 128 + y * 4 + wv) * 16) * 512 + l * 8;

  short8 P1[4], P3[4], Q1[4], Q3[4];
  auto loadS = [&](short8* r1, short8* r3, int s) {   // s = quarter-K index [0,4)
#pragma unroll
    for (int q = 0; q < 4; ++q) {
      r1[q] = *(const short8*)(w1b + (size_t)(s * 4 + q) * 512);
      r3[q] = *(const short8*)(w3b + (size_t)(s * 4 + q) * 512);
    }
  };

  f32x4 au[2], av[2];
#pragma unroll
  for (int i = 0; i < 2; ++i) {
    au[i] = (f32x4){0.f, 0.f, 0.f, 0.f};
    av[i] = (f32x4){0.f, 0.f, 0.f, 0.f};
  }

  auto quartC = [&](const short8* r1, const short8* r3, int s) {
#pragma unroll
    for (int q = 0; q < 4; ++q) {
      int kf = s * 4 + q;
      short8 a[2];
#pragma unroll
      for (int i = 0; i < 2; ++i) {
        int r = i * 16 + (l & 15);
        int slot = kf * 4 + (l >> 4);
        int swz = (slot & 56) | ((slot & 7) ^ (r & 7));
        a[i] = *(const short8*)(sA + r * 512 + swz * 8);
      }
#pragma unroll
      for (int i = 0; i < 2; ++i) {
        au[i] = __builtin_amdgcn_mfma_f32_16x16x32_bf16(a[i], r1[q], au[i], 0, 0, 0);
        av[i] = __builtin_amdgcn_mfma_f32_16x16x32_bf16(a[i], r3[q], av[i], 0, 0, 0);
      }
    }
  };

  loadS(P1, P3, 0);
  __syncthreads();        // sA ready (the only barrier)
  loadS(Q1, Q3, 1);       // prefetch next quarter while computing current
  quartC(P1, P3, 0);
  loadS(P1, P3, 2);
  quartC(Q1, Q3, 1);
  loadS(Q1, Q3, 3);
  quartC(P1, P3, 2);
  quartC(Q1, Q3, 3);

  int cloc = l & 15, rb = (l >> 4) * 4;
  int col = y * 64 + wv * 16 + cloc;
#pragma unroll
  for (int i = 0; i < 2; ++i)
#pragma unroll
    for (int r = 0; r < 4; ++r) {
      int gr = g0 + i * 16 + rb + r;
      if (gr < lim) {
        float uu = au[i][r], vv = av[i][r];
        float hh = (uu / (1.f + expf(-uu))) * vv;
        hbuf[(size_t)gr * F_DIM + col] = f2bf(hh);
      }
    }
}

// ---- pass 2: y = h @ W2; BM=64 BN=32 BK=128; XCD owns 5 m-tiles x all panels ----
__global__ __launch_bounds__(256, 3) void k_ffn2(const unsigned short* __restrict__ hbuf,
                                                 const unsigned short* __restrict__ w2f,
                                                 const int* __restrict__ cntp,
                                                 const int* __restrict__ basep,
                                                 const int* __restrict__ list,
                                                 const int* __restrict__ tl1,
                                                 const int* __restrict__ ntl,
                                                 const float* __restrict__ wbuf,
                                                 float* __restrict__ out) {
  int L = blockIdx.x;
  int c = L & 7, q = L >> 3;           // q in [0,80)
  int x = c * 5 + (q % 5);             // m-tile: XCD c owns [5c, 5c+5)
  int nt = q / 5;                      // 32-col d-panel [0,16)
  if (x >= ntl[0]) return;
  int pk = tl1[x];
  int e = pk >> 16, g0 = pk & 0xffff;
  int lim = basep[e] + cntp[e];
  __shared__ unsigned short sA[2 * 8192];   // 2 x 16 KB chunks [64][128], swizzled
  int tid = threadIdx.x, wv = tid >> 6, l = tid & 63;
  int wr = wv >> 1, wc = wv & 1;

  auto stage = [&](int buf, int ck) {
#pragma unroll
    for (int it = 0; it < 4; ++it) {
      int row0 = it * 16 + wv * 4;             // wave-uniform
      int row = row0 + (l >> 4);
      int gr = g0 + row; if (gr > T_TOK - 1) gr = T_TOK - 1;
      int sl = (l & 8) | ((l & 7) ^ (row & 7));
      gld16(hbuf + (size_t)gr * F_DIM + ck * 128 + sl * 8, sA + buf * 8192 + row0 * 128);
    }
  };

  const unsigned short* b2p = w2f + ((size_t)(e * 32 + nt * 2 + wc) * 64) * 512 + l * 8;

  short8 Ba[4], Bb[4];
  auto loadB = [&](short8* B, int ck) {
#pragma unroll
    for (int kk = 0; kk < 4; ++kk)
      B[kk] = *(const short8*)(b2p + (size_t)(ck * 4 + kk) * 512);
  };

  f32x4 acc[2];
  acc[0] = (f32x4){0.f, 0.f, 0.f, 0.f};
  acc[1] = (f32x4){0.f, 0.f, 0.f, 0.f};

  auto compute = [&](const short8* B, int cur) {
#pragma unroll
    for (int kk = 0; kk < 4; ++kk) {
      short8 a[2];
#pragma unroll
      for (int i = 0; i < 2; ++i) {
        int r = wr * 32 + i * 16 + (l & 15);
        int slot = kk * 4 + (l >> 4);
        int swz = (slot & 8) | ((slot & 7) ^ (r & 7));
        a[i] = *(const short8*)(sA + cur * 8192 + r * 128 + swz * 8);
      }
      acc[0] = __builtin_amdgcn_mfma_f32_16x16x32_bf16(a[0], B[kk], acc[0], 0, 0, 0);
      acc[1] = __builtin_amdgcn_mfma_f32_16x16x32_bf16(a[1], B[kk], acc[1], 0, 0, 0);
    }
  };

  stage(0, 0);
  loadB(Ba, 0);
  __syncthreads();
  int cur = 0;
  for (int ck = 0; ck < 16; ck += 2) {
    stage(cur ^ 1, ck + 1);
    loadB(Bb, ck + 1);
    compute(Ba, cur);
    __syncthreads();
    cur ^= 1;
    if (ck + 2 < 16) {
      stage(cur ^ 1, ck + 2);
      loadB(Ba, ck + 2);
    }
    compute(Bb, cur);
    __syncthreads();
    cur ^= 1;
  }

  int cloc = l & 15, rb = (l >> 4) * 4;
#pragma unroll
  for (int i = 0; i < 2; ++i)
#pragma unroll
    for (int r = 0; r < 4; ++r) {
      int gr = g0 + wr * 32 + i * 16 + rb + r;
      if (gr < lim) {
        int tok = list[gr];
        out[(size_t)tok * D_DIM + nt * 32 + wc * 16 + cloc] = wbuf[tok] * acc[i][r];
      }
    }
}

// ---------------- launch ----------------
extern "C" void kernel_launch(void* const* d_in, const int* in_sizes, int n_in,
                              void* d_out, int out_size, void* d_ws, size_t ws_size,
                              hipStream_t stream) {
  const float* x  = (const float*)d_in[0];
  const float* Wg = (const float*)d_in[1];
  const float* W1 = (const float*)d_in[2];
  const float* W2 = (const float*)d_in[3];
  const float* W3 = (const float*)d_in[4];
  float* out = (float*)d_out;
  char* ws = (char*)d_ws;

  int*            jbuf  = (int*)(ws + 0);
  float*          wbuf  = (float*)(ws + 8192);
  int*            cntp  = (int*)(ws + 16384);
  int*            basep = (int*)(ws + 16448);
  int*            list  = (int*)(ws + 16640);      // int[2048]
  int*            tl1   = (int*)(ws + 24832);      // int[40]
  int*            tl32  = (int*)(ws + 25088);      // int[80]
  int*            ntl   = (int*)(ws + 25600);      // int[2]
  unsigned short* xb    = (unsigned short*)(ws + 32768);                          // bf16 [2048][512]
  unsigned short* w1f   = (unsigned short*)(ws + 32768 + 2097152);                // frag [8][128][16][64][8]
  unsigned short* w3f   = (unsigned short*)(ws + 32768 + 2097152 + 16777216);
  unsigned short* w2f   = (unsigned short*)(ws + 32768 + 2097152 + 2 * 16777216); // frag [8][32][64][64][8]
  unsigned short* hbuf  = (unsigned short*)(ws + 32768 + 2097152 + 3 * 16777216); // bf16 [2048][2048]

  k_prep<<<dim3(1280), dim3(256), 0, stream>>>(x, Wg, W1, W3, jbuf, wbuf, xb, w1f, w3f);
  k_bucket<<<dim3(1), dim3(256), 0, stream>>>(jbuf, cntp, basep, list, tl1, tl32, ntl);
  k_ffn1w2<<<dim3(3584), dim3(256), 0, stream>>>(xb, w1f, w3f, W2, w2f, cntp, basep, list, tl32, ntl, hbuf);
  k_ffn2<<<dim3(640), dim3(256), 0, stream>>>(hbuf, w2f, cntp, basep, list, tl1, ntl, wbuf, out);
}

// Round 23
// 74.899 us; speedup vs baseline: 1.0139x; 1.0139x over previous
//
#include <hip/hip_runtime.h>
#include <hip/hip_bf16.h>
#include <math.h>

typedef __attribute__((ext_vector_type(8))) short short8;
typedef __attribute__((ext_vector_type(4))) float f32x4;

#define T_TOK 2048
#define D_DIM 512
#define F_DIM 2048
#define E_NUM 8
#define MAXT1 40   // == sum_e ceil(cnt_e/64) upper bound (32 + 7 rounding)

__device__ __forceinline__ unsigned short f2bf(float f) {
  union { float f; unsigned u; } c; c.f = f;
  unsigned u = c.u;
  return (unsigned short)((u + 0x7fffu + ((u >> 16) & 1u)) >> 16);
}

__device__ __forceinline__ void gld16(const void* g, void* l) {
  __builtin_amdgcn_global_load_lds((const __attribute__((address_space(1))) int*)g,
                                   (__attribute__((address_space(3))) int*)l, 16, 0, 0);
}

// ---- prep: route (blocks 0..255) + wfrag1 W1/W3 dbuf 2-tiles (256..1279) ----
__global__ __launch_bounds__(256) void k_prep(const float* __restrict__ xin,
                                              const float* __restrict__ Wg,
                                              const float* __restrict__ W1,
                                              const float* __restrict__ W3,
                                              int* __restrict__ jbuf,
                                              float* __restrict__ wbuf,
                                              unsigned short* __restrict__ xb,
                                              unsigned short* __restrict__ w1f,
                                              unsigned short* __restrict__ w3f) {
  __shared__ float4 tile4[2][64 * 32];   // 64 KB (route blocks don't touch it)
  int bz = blockIdx.x, tid = threadIdx.x;

  if (bz < 256) {
    // ---- routing: logits (32-way K-split) + top-2 + weight; converts x->bf16 ----
    int gid = bz * 256 + tid;
    int t = gid >> 5, seg = gid & 31;
    const float* xp = xin + (size_t)t * D_DIM + seg * 16;
    unsigned short* xo = xb + (size_t)t * D_DIM + seg * 16;
    float acc[8];
#pragma unroll
    for (int e = 0; e < 8; ++e) acc[e] = 0.f;
#pragma unroll
    for (int i = 0; i < 4; ++i) {
      float4 v = *(const float4*)(xp + i * 4);
      ushort4 o;
      o.x = f2bf(v.x); o.y = f2bf(v.y); o.z = f2bf(v.z); o.w = f2bf(v.w);
      *(ushort4*)(xo + i * 4) = o;
      const float* xs = (const float*)&v;
#pragma unroll
      for (int q = 0; q < 4; ++q) {
        int d = seg * 16 + i * 4 + q;
        const float4* wr = (const float4*)(Wg + (size_t)d * 8);
        float4 w0 = wr[0], w1 = wr[1];
        acc[0] += xs[q] * w0.x; acc[1] += xs[q] * w0.y;
        acc[2] += xs[q] * w0.z; acc[3] += xs[q] * w0.w;
        acc[4] += xs[q] * w1.x; acc[5] += xs[q] * w1.y;
        acc[6] += xs[q] * w1.z; acc[7] += xs[q] * w1.w;
      }
    }
#pragma unroll
    for (int off = 1; off < 32; off <<= 1)
#pragma unroll
      for (int e = 0; e < 8; ++e) acc[e] += __shfl_xor(acc[e], off);
    if (seg == 0) {
      float l0 = -1e30f, l1 = -1e30f; int i0 = 0, i1 = 0;
#pragma unroll
      for (int e = 0; e < 8; ++e) {
        float l = acc[e];
        if (l > l0) { l1 = l0; i1 = i0; l0 = l; i0 = e; }
        else if (l > l1) { l1 = l; i1 = e; }
      }
      int j; float w;
      if (i0 > i1) { j = i0; w = 1.f / (1.f + expf(l1 - l0)); }
      else         { j = i1; w = 1.f / (1.f + expf(l0 - l1)); }
      jbuf[t] = j; wbuf[t] = w;
    }
    return;
  }

  // ---- wfrag1: W1/W3 [512][2048] -> frag bf16; 2 k-tiles per block, dbuf ----
  int idx = bz - 256;            // [0,1024)
  int z = idx >> 6, rem = idx & 63;
  const int K = 512, N = 2048;
  int n0 = (rem & 15) * 128, k0 = (rem >> 4) * 128;
  size_t zsz = (size_t)(K / 32) * (N / 16) * 512;
  const float* in; unsigned short* out;
  if (z < 8) { in = W1 + (size_t)z * K * N;       out = w1f + (size_t)z * zsz; }
  else       { in = W3 + (size_t)(z - 8) * K * N; out = w3f + (size_t)(z - 8) * zsz; }

  int lr = tid >> 5, lc = tid & 31;
  int wv = tid >> 6, l = tid & 63;
  int n4l = (l & 15) >> 2, nr = l & 3, kg = (l >> 4) * 8;

  auto loadT = [&](int buf, int kb0) {
#pragma unroll
    for (int it = 0; it < 8; ++it) {
      int row = it * 8 + lr;
      float4 v = *(const float4*)(in + (size_t)(kb0 + row) * N + n0 + lc * 4);
      tile4[buf][row * 32 + ((lc + (row >> 3) * 4) & 31)] = v;   // rotation swizzle
    }
  };
  auto storeT = [&](int buf, int kb0) {
    const float* tf = (const float*)&tile4[buf][0];
#pragma unroll
    for (int q = 0; q < 4; ++q) {
      int fid = wv * 4 + q;
      int nb = fid >> 1, kb = fid & 1;
      int n4 = nb * 4 + n4l;
      short8 o;
#pragma unroll
      for (int j = 0; j < 8; ++j) {
        int k = kb * 32 + kg + j;
        int slot = k * 32 + ((n4 + (k >> 3) * 4) & 31);
        o[j] = (short)f2bf(tf[slot * 4 + nr]);
      }
      unsigned short* op = out + (((size_t)(n0 / 16 + nb) * (K / 32)) + (kb0 / 32 + kb)) * 512 + l * 8;
      *(short8*)op = o;
    }
  };

  loadT(0, k0);
  __syncthreads();
  loadT(1, k0 + 64);    // issue next tile's loads; latency hides under storeT(0)
  storeT(0, k0);
  __syncthreads();
  storeT(1, k0 + 64);
}

// ---- bucket: counts, bases, compact token list, compact tile list (BM=64) ----
__global__ __launch_bounds__(256) void k_bucket(const int* __restrict__ jbuf,
                                                int* __restrict__ cntp,
                                                int* __restrict__ basep,
                                                int* __restrict__ list,
                                                int* __restrict__ tl1,
                                                int* __restrict__ ntl) {
  __shared__ int scnt[8], scur[8];
  int tid = threadIdx.x;
  if (tid < 8) scnt[tid] = 0;
  __syncthreads();
  for (int t = tid; t < T_TOK; t += 256) atomicAdd(&scnt[jbuf[t]], 1);
  __syncthreads();
  if (tid == 0) {
    int run = 0;
    for (int e = 0; e < 8; ++e) {
      cntp[e] = scnt[e]; basep[e] = run; scur[e] = run;
      run += scnt[e];
    }
    int n1 = 0, bb = 0;
    for (int e = 0; e < 8; ++e) {
      for (int m = 0; m < scnt[e]; m += 64) tl1[n1++] = (e << 16) | (bb + m);
      bb += scnt[e];
    }
    ntl[0] = n1;
  }
  __syncthreads();
  for (int t = tid; t < T_TOK; t += 256) {
    int j = jbuf[t];
    int p = atomicAdd(&scur[j], 1);
    list[p] = t;
  }
}

// ---- fused: ffn1 1x4 waves 2-deep B prefetch (0..1279) + wfrag2 dbuf (1280..1791) ----
__global__ __launch_bounds__(256, 2) void k_ffn1w2(const unsigned short* __restrict__ xb,
                                                   const unsigned short* __restrict__ w1f,
                                                   const unsigned short* __restrict__ w3f,
                                                   const float* __restrict__ W2,
                                                   unsigned short* __restrict__ w2f,
                                                   const int* __restrict__ cntp,
                                                   const int* __restrict__ basep,
                                                   const int* __restrict__ list,
                                                   const int* __restrict__ tl1,
                                                   const int* __restrict__ ntl,
                                                   unsigned short* __restrict__ hbuf) {
  __shared__ __align__(16) unsigned short sA[64 * 512];   // 64 KB (ffn1 A / wfrag2 dbuf tiles)
  int tid = threadIdx.x, wv = tid >> 6, l = tid & 63;

  if (blockIdx.x >= 1280) {
    // ---- wfrag2: W2 [2048][512] -> frag bf16; 2 k-tiles per block, dbuf ----
    int idx = blockIdx.x - 1280;   // [0,512)
    int z = idx >> 6, rem = idx & 63;
    const int K = 2048, N = 512;
    int n0 = (rem & 3) * 128, k0 = (rem >> 2) * 128;
    size_t zsz = (size_t)(K / 32) * (N / 16) * 512;
    const float* in = W2 + (size_t)z * K * N;
    unsigned short* out = w2f + (size_t)z * zsz;
    float4* tile4 = (float4*)sA;   // [2][64*32]

    int lr = tid >> 5, lc = tid & 31;
    int n4l = (l & 15) >> 2, nr = l & 3, kg = (l >> 4) * 8;

    auto loadT = [&](int buf, int kb0) {
#pragma unroll
      for (int it = 0; it < 8; ++it) {
        int row = it * 8 + lr;
        float4 v = *(const float4*)(in + (size_t)(kb0 + row) * N + n0 + lc * 4);
        tile4[buf * 2048 + row * 32 + ((lc + (row >> 3) * 4) & 31)] = v;
      }
    };
    auto storeT = [&](int buf, int kb0) {
      const float* tf = (const float*)&tile4[buf * 2048];
#pragma unroll
      for (int q = 0; q < 4; ++q) {
        int fid = wv * 4 + q;
        int nb = fid >> 1, kb = fid & 1;
        int n4 = nb * 4 + n4l;
        short8 o;
#pragma unroll
        for (int j = 0; j < 8; ++j) {
          int k = kb * 32 + kg + j;
          int slot = k * 32 + ((n4 + (k >> 3) * 4) & 31);
          o[j] = (short)f2bf(tf[slot * 4 + nr]);
        }
        unsigned short* op = out + (((size_t)(n0 / 16 + nb) * (K / 32)) + (kb0 / 32 + kb)) * 512 + l * 8;
        *(short8*)op = o;
      }
    };

    loadT(0, k0);
    __syncthreads();
    loadT(1, k0 + 64);
    storeT(0, k0);
    __syncthreads();
    storeT(1, k0 + 64);
    return;
  }

  // ---- ffn1: A staged once; wave owns 64 rows x 16 cols; 2-deep B rotation ----
  int L = blockIdx.x;
  int b = (L & 7) * 160 + (L >> 3);    // XCD c owns y-groups [4c,4c+4) x all m-tiles
  int x = b % 40, y = b / 40;          // x: m-tile, y: 64-col group [0,32)
  if (x >= ntl[0]) return;
  int pk = tl1[x];
  int e = pk >> 16, g0 = pk & 0xffff;
  int lim = basep[e] + cntp[e];

  // one-time A stage: wave wv stages rows wv*16..+15 (swizzled source slots)
#pragma unroll
  for (int it = 0; it < 16; ++it) {
    int row = wv * 16 + it;
    int gr = g0 + row; if (gr >= lim) gr = lim - 1;
    int tok = list[gr];
    int slot = (l & 56) | ((l & 7) ^ (row & 7));
    gld16(xb + (size_t)tok * D_DIM + slot * 8, sA + row * 512);
  }

  // per-wave private B fragment column block: nb = y*4 + wv
  const unsigned short* w1b = w1f + ((size_t)(e * 128 + y * 4 + wv) * 16) * 512 + l * 8;
  const unsigned short* w3b = w3f + ((size_t)(e * 128 + y * 4 + wv) * 16) * 512 + l * 8;

  short8 P1[4], P3[4], Q1[4], Q3[4], R1[4], R3[4];
  auto loadS = [&](short8* r1, short8* r3, int s) {   // s = quarter-K index [0,4)
#pragma unroll
    for (int q = 0; q < 4; ++q) {
      r1[q] = *(const short8*)(w1b + (size_t)(s * 4 + q) * 512);
      r3[q] = *(const short8*)(w3b + (size_t)(s * 4 + q) * 512);
    }
  };

  f32x4 au[4], av[4];
#pragma unroll
  for (int i = 0; i < 4; ++i) {
    au[i] = (f32x4){0.f, 0.f, 0.f, 0.f};
    av[i] = (f32x4){0.f, 0.f, 0.f, 0.f};
  }

  auto quartC = [&](const short8* r1, const short8* r3, int s) {
#pragma unroll
    for (int q = 0; q < 4; ++q) {
      int kf = s * 4 + q;
      short8 a[4];
#pragma unroll
      for (int i = 0; i < 4; ++i) {
        int r = i * 16 + (l & 15);
        int slot = kf * 4 + (l >> 4);
        int swz = (slot & 56) | ((slot & 7) ^ (r & 7));
        a[i] = *(const short8*)(sA + r * 512 + swz * 8);
      }
#pragma unroll
      for (int i = 0; i < 4; ++i) {
        au[i] = __builtin_amdgcn_mfma_f32_16x16x32_bf16(a[i], r1[q], au[i], 0, 0, 0);
        av[i] = __builtin_amdgcn_mfma_f32_16x16x32_bf16(a[i], r3[q], av[i], 0, 0, 0);
      }
    }
  };

  // 2-deep rotation: while computing s, s+1 is ready and s+2 is in flight
  loadS(P1, P3, 0);
  loadS(Q1, Q3, 1);       // both ride under the A-stage barrier drain
  __syncthreads();        // sA ready (the only barrier)
  loadS(R1, R3, 2);
  quartC(P1, P3, 0);
  loadS(P1, P3, 3);
  quartC(Q1, Q3, 1);
  quartC(R1, R3, 2);
  quartC(P1, P3, 3);

  int cloc = l & 15, rb = (l >> 4) * 4;
  int col = y * 64 + wv * 16 + cloc;
#pragma unroll
  for (int i = 0; i < 4; ++i)
#pragma unroll
    for (int r = 0; r < 4; ++r) {
      int gr = g0 + i * 16 + rb + r;
      if (gr < lim) {
        float uu = au[i][r], vv = av[i][r];
        float hh = (uu / (1.f + expf(-uu))) * vv;
        hbuf[(size_t)gr * F_DIM + col] = f2bf(hh);
      }
    }
}

// ---- pass 2: y = h @ W2; BM=64 BN=32 BK=128; XCD owns 5 m-tiles x all panels ----
__global__ __launch_bounds__(256, 3) void k_ffn2(const unsigned short* __restrict__ hbuf,
                                                 const unsigned short* __restrict__ w2f,
                                                 const int* __restrict__ cntp,
                                                 const int* __restrict__ basep,
                                                 const int* __restrict__ list,
                                                 const int* __restrict__ tl1,
                                                 const int* __restrict__ ntl,
                                                 const float* __restrict__ wbuf,
                                                 float* __restrict__ out) {
  int L = blockIdx.x;
  int c = L & 7, q = L >> 3;           // q in [0,80)
  int x = c * 5 + (q % 5);             // m-tile: XCD c owns [5c, 5c+5)
  int nt = q / 5;                      // 32-col d-panel [0,16)
  if (x >= ntl[0]) return;
  int pk = tl1[x];
  int e = pk >> 16, g0 = pk & 0xffff;
  int lim = basep[e] + cntp[e];
  __shared__ unsigned short sA[2 * 8192];   // 2 x 16 KB chunks [64][128], swizzled
  int tid = threadIdx.x, wv = tid >> 6, l = tid & 63;
  int wr = wv >> 1, wc = wv & 1;

  auto stage = [&](int buf, int ck) {
#pragma unroll
    for (int it = 0; it < 4; ++it) {
      int row0 = it * 16 + wv * 4;             // wave-uniform
      int row = row0 + (l >> 4);
      int gr = g0 + row; if (gr > T_TOK - 1) gr = T_TOK - 1;
      int sl = (l & 8) | ((l & 7) ^ (row & 7));
      gld16(hbuf + (size_t)gr * F_DIM + ck * 128 + sl * 8, sA + buf * 8192 + row0 * 128);
    }
  };

  // w2f frag (nb, kf) at (nb*64 + kf)*512; nb = nt*2 + wc
  const unsigned short* b2p = w2f + ((size_t)(e * 32 + nt * 2 + wc) * 64) * 512 + l * 8;

  short8 Ba[4], Bb[4];
  auto loadB = [&](short8* B, int ck) {
#pragma unroll
    for (int kk = 0; kk < 4; ++kk)
      B[kk] = *(const short8*)(b2p + (size_t)(ck * 4 + kk) * 512);
  };

  f32x4 acc[2];
  acc[0] = (f32x4){0.f, 0.f, 0.f, 0.f};
  acc[1] = (f32x4){0.f, 0.f, 0.f, 0.f};

  auto compute = [&](const short8* B, int cur) {
#pragma unroll
    for (int kk = 0; kk < 4; ++kk) {
      short8 a[2];
#pragma unroll
      for (int i = 0; i < 2; ++i) {
        int r = wr * 32 + i * 16 + (l & 15);
        int slot = kk * 4 + (l >> 4);
        int swz = (slot & 8) | ((slot & 7) ^ (r & 7));
        a[i] = *(const short8*)(sA + cur * 8192 + r * 128 + swz * 8);
      }
      acc[0] = __builtin_amdgcn_mfma_f32_16x16x32_bf16(a[0], B[kk], acc[0], 0, 0, 0);
      acc[1] = __builtin_amdgcn_mfma_f32_16x16x32_bf16(a[1], B[kk], acc[1], 0, 0, 0);
    }
  };

  stage(0, 0);
  loadB(Ba, 0);
  __syncthreads();
  int cur = 0;
  for (int ck = 0; ck < 16; ck += 2) {
    stage(cur ^ 1, ck + 1);
    loadB(Bb, ck + 1);
    compute(Ba, cur);
    __syncthreads();
    cur ^= 1;
    if (ck + 2 < 16) {
      stage(cur ^ 1, ck + 2);
      loadB(Ba, ck + 2);
    }
    compute(Bb, cur);
    __syncthreads();
    cur ^= 1;
  }

  int cloc = l & 15, rb = (l >> 4) * 4;
#pragma unroll
  for (int i = 0; i < 2; ++i)
#pragma unroll
    for (int r = 0; r < 4; ++r) {
      int gr = g0 + wr * 32 + i * 16 + rb + r;
      if (gr < lim) {
        int tok = list[gr];
        out[(size_t)tok * D_DIM + nt * 32 + wc * 16 + cloc] = wbuf[tok] * acc[i][r];
      }
    }
}

// ---------------- launch ----------------
extern "C" void kernel_launch(void* const* d_in, const int* in_sizes, int n_in,
                              void* d_out, int out_size, void* d_ws, size_t ws_size,
                              hipStream_t stream) {
  const float* x  = (const float*)d_in[0];
  const float* Wg = (const float*)d_in[1];
  const float* W1 = (const float*)d_in[2];
  const float* W2 = (const float*)d_in[3];
  const float* W3 = (const float*)d_in[4];
  float* out = (float*)d_out;
  char* ws = (char*)d_ws;

  int*            jbuf  = (int*)(ws + 0);
  float*          wbuf  = (float*)(ws + 8192);
  int*            cntp  = (int*)(ws + 16384);
  int*            basep = (int*)(ws + 16448);
  int*            list  = (int*)(ws + 16640);      // int[2048]
  int*            tl1   = (int*)(ws + 24832);      // int[40]
  int*            ntl   = (int*)(ws + 25600);      // int[2]
  unsigned short* xb    = (unsigned short*)(ws + 32768);                          // bf16 [2048][512]
  unsigned short* w1f   = (unsigned short*)(ws + 32768 + 2097152);                // frag [8][128][16][64][8]
  unsigned short* w3f   = (unsigned short*)(ws + 32768 + 2097152 + 16777216);
  unsigned short* w2f   = (unsigned short*)(ws + 32768 + 2097152 + 2 * 16777216); // frag [8][32][64][64][8]
  unsigned short* hbuf  = (unsigned short*)(ws + 32768 + 2097152 + 3 * 16777216); // bf16 [2048][2048]

  k_prep<<<dim3(1280), dim3(256), 0, stream>>>(x, Wg, W1, W3, jbuf, wbuf, xb, w1f, w3f);
  k_bucket<<<dim3(1), dim3(256), 0, stream>>>(jbuf, cntp, basep, list, tl1, ntl);
  k_ffn1w2<<<dim3(1792), dim3(256), 0, stream>>>(xb, w1f, w3f, W2, w2f, cntp, basep, list, tl1, ntl, hbuf);
  k_ffn2<<<dim3(640), dim3(256), 0, stream>>>(hbuf, w2f, cntp, basep, list, tl1, ntl, wbuf, out);
}